// Round 3
// baseline (157.358 us; speedup 1.0000x reference)
//
#include <hip/hip_runtime.h>

// Spatial transformer (affine grid + bilinear sample)
// fmap: (B=128, H=256, W=256, C=3) fp32
// theta: (B=128, 6) fp32
// out:  (B=128, OH=192, OW=192, C=3) fp32

constexpr int B_  = 128;
constexpr int H_  = 256;
constexpr int W_  = 256;
constexpr int C_  = 3;
constexpr int OH_ = 192;
constexpr int OW_ = 192;
constexpr int PIX_PER_IMG = OH_ * OW_;            // 36864
constexpr int BLOCKS_PER_IMG = PIX_PER_IMG / 256; // 144

__global__ __launch_bounds__(256) void stn_bilinear_kernel(
    const float* __restrict__ fmap,
    const float* __restrict__ theta,
    float* __restrict__ out)
{
    // b is block-uniform: each 256-thread block lies within one image.
    const int b    = blockIdx.x / BLOCKS_PER_IMG;
    const int blk  = blockIdx.x % BLOCKS_PER_IMG;
    const int pix  = blk * 256 + threadIdx.x;     // pixel index within image
    const int j    = pix % OW_;
    const int i    = pix / OW_;

    // theta row — scalar loads (b uniform)
    const float* th = theta + b * 6;
    const float t0 = th[0], t1 = th[1], t2 = th[2];
    const float t3 = th[3], t4 = th[4], t5 = th[5];

    // normalized grid coords, linspace(-1, 1, N)
    const float xt = -1.0f + 2.0f * (float)j / (float)(OW_ - 1);
    const float yt = -1.0f + 2.0f * (float)i / (float)(OH_ - 1);

    // affine transform
    const float xs = t0 * xt + t1 * yt + t2;
    const float ys = t3 * xt + t4 * yt + t5;

    // map to pixel space; reference scales by (max_x - 1) = 254
    const float x = 0.5f * (xs + 1.0f) * 254.0f;
    const float y = 0.5f * (ys + 1.0f) * 254.0f;

    const float x0 = floorf(x);
    const float y0 = floorf(y);

    int x0c = (int)x0;
    int y0c = (int)y0;
    int x1c = x0c + 1;
    int y1c = y0c + 1;
    x0c = min(max(x0c, 0), W_ - 1);
    x1c = min(max(x1c, 0), W_ - 1);
    y0c = min(max(y0c, 0), H_ - 1);
    y1c = min(max(y1c, 0), H_ - 1);

    // weights from CLIPPED coords (matches reference semantics)
    const float x0f = (float)x0c, x1f = (float)x1c;
    const float y0f = (float)y0c, y1f = (float)y1c;
    const float wa = (x1f - x) * (y1f - y);
    const float wb = (x1f - x) * (y - y0f);
    const float wc = (x - x0f) * (y1f - y);
    const float wd = (x - x0f) * (y - y0f);

    const float* base = fmap + (size_t)b * (H_ * W_ * C_);
    const int r0 = y0c * (W_ * C_), r1 = y1c * (W_ * C_);
    const int c0 = x0c * C_,        c1 = x1c * C_;
    const float* pa = base + r0 + c0;
    const float* pb = base + r1 + c0;
    const float* pc = base + r0 + c1;
    const float* pd = base + r1 + c1;

    float* o = out + ((size_t)b * PIX_PER_IMG + pix) * C_;
#pragma unroll
    for (int c = 0; c < C_; ++c) {
        o[c] = wa * pa[c] + wb * pb[c] + wc * pc[c] + wd * pd[c];
    }
}

extern "C" void kernel_launch(void* const* d_in, const int* in_sizes, int n_in,
                              void* d_out, int out_size, void* d_ws, size_t ws_size,
                              hipStream_t stream) {
    const float* fmap  = (const float*)d_in[0];
    const float* theta = (const float*)d_in[1];
    float* out = (float*)d_out;

    const int grid = B_ * BLOCKS_PER_IMG;
    stn_bilinear_kernel<<<grid, 256, 0, stream>>>(fmap, theta, out);
}